// Round 6
// baseline (474.295 us; speedup 1.0000x reference)
//
#include <hip/hip_runtime.h>
#include <stdint.h>

#define S_DIM 8192
#define K_DIM 4096
#define N_DIM 4096

#define BM 256
#define BN 256
#define BK 128   // bytes of K per staging stage (2 MFMA k-steps of 64)

typedef int v4i __attribute__((ext_vector_type(4)));

// ---------------------------------------------------------------------------
// One launch: pack x (int32->int8), pack w, and copy scale_y to the output
// tail. Pack destination is contiguous in ws: [x packed | w packed].
__global__ void prep(const int* __restrict__ x, const int* __restrict__ w,
                     const float* __restrict__ sy,
                     int* __restrict__ dst, float* __restrict__ out) {
    const int nx = S_DIM * K_DIM / 4;
    const int nw = N_DIM * K_DIM / 4;
    int i = blockIdx.x * 256 + threadIdx.x;
    if (i < nx) {
        int4 a = ((const int4*)x)[i];
        dst[i] = (a.x & 0xFF) | ((a.y & 0xFF) << 8) | ((a.z & 0xFF) << 16)
               | ((a.w & 0xFF) << 24);
    } else if (i < nx + nw) {
        int4 a = ((const int4*)w)[i - nx];
        dst[i] = (a.x & 0xFF) | ((a.y & 0xFF) << 8) | ((a.z & 0xFF) << 16)
               | ((a.w & 0xFF) << 24);
    } else {
        int j = i - nx - nw;
        if (j < S_DIM) out[(size_t)S_DIM * N_DIM + j] = sy[j];
    }
}

// scale_y tail only (used by the no-workspace fallback path)
__global__ void copy_sy(const float* __restrict__ sy, float* __restrict__ out) {
    int i = blockIdx.x * blockDim.x + threadIdx.x;
    if (i < S_DIM) out[(size_t)S_DIM * N_DIM + i] = sy[i];
}

// ---------------------------------------------------------------------------
__device__ __forceinline__ void g2lds16(const void* g, void* l) {
    __builtin_amdgcn_global_load_lds((const __attribute__((address_space(1))) void*)g,
                                     (__attribute__((address_space(3))) void*)l,
                                     16, 0, 0);
}

// ---------------------------------------------------------------------------
// 256x256 tile i8 MFMA GEMM, double-buffered LDS, one barrier per K-stage.
// 4 waves in 2x2; each wave 128x128 as 8x8 tiles of mfma_i32_16x16x64_i8
// (the shape verified exact since R1). Register blocking 8x8 cuts LDS
// reads/MFMA to 0.25 KB (R5's measured limiter was the ds_read_b128 pipe at
// ~85 B/cy/CU) -> LDS (~1.5-2.2k cy/stage) now UNDER MFMA (2343 cy/stage):
// first MFMA-bound configuration. Double buffer (2x64KB LDS, 160KB pool)
// lets stage s+1's global_load_lds fly during stage s's compute; the
// mandatory vmcnt(0) at the single per-stage barrier then finds them done.
// acc 8x8x4 = 256 VGPR -> 1 wave/SIMD by design; 64 independent acc chains
// keep the MFMA pipe saturated.
// Swizzle rule (validated R2/R4/R5: zero conflicts): within each 8-lane
// group the chunk slot (c ^ (row&7)) is a permutation mod 8.
__launch_bounds__(256, 1)
__global__ void gemm_i8(const signed char* __restrict__ xp,
                        const signed char* __restrict__ wp,
                        const float* __restrict__ sx,
                        const float* __restrict__ sw,
                        const float* __restrict__ sy,
                        float* __restrict__ out) {
    __shared__ __align__(16) signed char As[2][BM * BK];   // 2 x 32 KB
    __shared__ __align__(16) signed char Bs[2][BN * BK];   // 2 x 32 KB

    const int tid  = threadIdx.x;
    const int lane = tid & 63;
    const int quad = lane >> 4;    // 0..3 -> 16B k-chunk within a 64B k-step
    const int l16  = lane & 15;    // row (A) / col (B) within 16
    const int wave = tid >> 6;     // 0..3
    const int wm = wave >> 1;      // wave m (2): 128-row slab
    const int wn = wave & 1;       // wave n (2): 128-col slab
    const int bn = blockIdx.x;     // fast axis: XCD k hosts bn in {k, k+8}
    const int bm = blockIdx.y;     //   -> 2 B-tiles (4MB) resident per XCD L2

    const signed char* aG = xp + (size_t)(bm * BM) * K_DIM;
    const signed char* bG = wp + (size_t)(bn * BN) * K_DIM;

    // Hoisted per-thread staging offsets: each operand tile = 2048 chunks of
    // 16B (256 rows x 8 chunks); thread stages 8 chunks per operand per stage.
    int sOff[8];
#pragma unroll
    for (int i = 0; i < 8; i++) {
        int li = i * 256 + tid;
        int row = li >> 3, c = li & 7, g = c ^ (row & 7);
        sOff[i] = row * K_DIM + (g << 4);
    }

    v4i acc[8][8];
#pragma unroll
    for (int i = 0; i < 8; i++)
#pragma unroll
        for (int j = 0; j < 8; j++) acc[i][j] = 0;

    // prologue: stage 0 into buffer 0
#pragma unroll
    for (int i = 0; i < 8; i++)
        g2lds16(aG + sOff[i], &As[0][(i * 256 + tid) * 16]);
#pragma unroll
    for (int i = 0; i < 8; i++)
        g2lds16(bG + sOff[i], &Bs[0][(i * 256 + tid) * 16]);

    const int NSTAGE = K_DIM / BK;   // 32
    for (int s = 0; s < NSTAGE; s++) {
        __syncthreads();  // drains stage-s loads; prior readers of buf s+1 done
        if (s + 1 < NSTAGE) {
            const int kk = (s + 1) * BK;
            const int b  = (s + 1) & 1;
#pragma unroll
            for (int i = 0; i < 8; i++)
                g2lds16(aG + sOff[i] + kk, &As[b][(i * 256 + tid) * 16]);
#pragma unroll
            for (int i = 0; i < 8; i++)
                g2lds16(bG + sOff[i] + kk, &Bs[b][(i * 256 + tid) * 16]);
        }
        const signed char* Ab = As[s & 1];
        const signed char* Bb = Bs[s & 1];

#pragma unroll
        for (int ks = 0; ks < 2; ks++) {       // two 64B k-steps per stage
            const int slot = ((ks << 2) | quad) ^ (l16 & 7);
            v4i af[8], bf[8];
#pragma unroll
            for (int t = 0; t < 8; t++)
                af[t] = *(const v4i*)(Ab + (wm * 128 + t * 16 + l16) * BK
                                         + (slot << 4));
#pragma unroll
            for (int u = 0; u < 8; u++)
                bf[u] = *(const v4i*)(Bb + (wn * 128 + u * 16 + l16) * BK
                                         + (slot << 4));
#pragma unroll
            for (int mt = 0; mt < 8; mt++)
#pragma unroll
                for (int nt = 0; nt < 8; nt++)
                    acc[mt][nt] = __builtin_amdgcn_mfma_i32_16x16x64_i8(
                        af[mt], bf[nt], acc[mt][nt], 0, 0, 0);
        }
    }

    // Epilogue: C/D layout (verified exact since R1): col = lane&15,
    // row = quad*4 + reg.
    const int s_base = bm * BM + wm * 128;
    const int n_base = bn * BN + wn * 128;
#pragma unroll
    for (int mt = 0; mt < 8; mt++) {
#pragma unroll
        for (int r = 0; r < 4; r++) {
            int srow = s_base + mt * 16 + quad * 4 + r;
            float rs = sx[srow] / sy[srow];
            float* orow = out + (size_t)srow * N_DIM;
#pragma unroll
            for (int nt = 0; nt < 8; nt++) {
                int n = n_base + nt * 16 + l16;
                float v = rintf((float)acc[mt][nt][r] * (rs * sw[n]));
                v = fminf(fmaxf(v, -128.f), 127.f);
                orow[n] = v;
            }
        }
    }
}

// ---------------------------------------------------------------------------
// Correctness fallback if the workspace is too small for packed operands.
__global__ void gemm_naive(const int* __restrict__ x, const int* __restrict__ w,
                           const float* __restrict__ sx, const float* __restrict__ sw,
                           const float* __restrict__ sy, float* __restrict__ out) {
    int n = blockIdx.x * blockDim.x + threadIdx.x;
    int s = blockIdx.y;
    const int4* xr = (const int4*)(x + (size_t)s * K_DIM);
    const int4* wr = (const int4*)(w + (size_t)n * K_DIM);
    int acc = 0;
    for (int k = 0; k < K_DIM / 4; k++) {
        int4 a = xr[k], b = wr[k];
        acc += a.x * b.x + a.y * b.y + a.z * b.z + a.w * b.w;
    }
    float v = rintf((float)acc * (sx[s] / sy[s] * sw[n]));
    out[(size_t)s * N_DIM + n] = fminf(fmaxf(v, -128.f), 127.f);
}

// ---------------------------------------------------------------------------
extern "C" void kernel_launch(void* const* d_in, const int* in_sizes, int n_in,
                              void* d_out, int out_size, void* d_ws, size_t ws_size,
                              hipStream_t stream) {
    const int*   x  = (const int*)d_in[0];     // [S, K] int8 values widened to int32
    const int*   wq = (const int*)d_in[1];     // [N, K]
    const float* sx = (const float*)d_in[2];   // [S]
    const float* sw = (const float*)d_in[3];   // [N]
    const float* sy = (const float*)d_in[4];   // [S]
    float* out = (float*)d_out;                // [S*N out_q] ++ [S scale_y], float32

    const size_t need = (size_t)S_DIM * K_DIM + (size_t)N_DIM * K_DIM;  // 48 MiB
    if (ws_size >= need) {
        signed char* xp = (signed char*)d_ws;
        signed char* wp = xp + (size_t)S_DIM * K_DIM;
        const int nprep = (S_DIM * K_DIM / 4) + (N_DIM * K_DIM / 4) + S_DIM;
        prep<<<dim3((nprep + 255) / 256), dim3(256), 0, stream>>>(
            x, wq, sy, (int*)xp, out);
        gemm_i8<<<dim3(N_DIM / BN, S_DIM / BM), dim3(256), 0, stream>>>(
            xp, wp, sx, sw, sy, out);
    } else {
        copy_sy<<<dim3((S_DIM + 255) / 256), dim3(256), 0, stream>>>(sy, out);
        gemm_naive<<<dim3(N_DIM / 256, S_DIM), dim3(256), 0, stream>>>(
            x, wq, sx, sw, sy, out);
    }
}